// Round 15
// baseline (570.424 us; speedup 1.0000x reference)
//
#include <hip/hip_runtime.h>

// ---------------- problem constants ----------------
#define T_TOK 8192      // B*S tokens
#define D_DIM 1024
#define F_DIM 4096
#define E_EXP 8
#define DT_DIM 256
#define GBLK 256        // gating blocks (32 tokens each)

// ---------------- workspace layout (bytes) ----------------
#define A_XB   0u                    // bf16 X   [8192][1024]   16,777,216
#define A_WT   16777216u             // bf16 W1T (and W2T in small-ws mode)
#define A_H    83886080u             // bf16 h   [17408][4096] 142,606,336
#define A_Y    226492416u            // bf16 Y   [17408][1024]  (unused now)
#define A_META 262144000u
#define A_W2T  262498560u            // optional separate W2T
#define W2T_NEED (262498560ull + 67108864ull)
// meta byte offsets
#define MO_FILL   0        // 8 ints (atomic fill cursors)
#define MO_PB     64       // 9 ints (expert segment bases)
#define MO_NT     128      // 1 int
#define MO_PARTP  256      // f32[256][8] per-block prob partials (8KB)
#define MO_PARTC  8448     // int[256][8] per-block count partials (8KB)
#define MO_TILEE  16640    // int[160]
#define MO_TILERB 17664    // int[160]
#define MO_ROUTEE 18688    // int[16384]
#define MO_ROUTEW 84224    // f32[16384]
#define MO_TSLOT  149760   // int[16384]
#define MO_PTOK   215296   // int[17408]
#define MO_WSLOT  284928   // f32[17408] per-slot combine weight
#define META_BYTES 354560

using bf16x8 = __attribute__((ext_vector_type(8))) short;
using f32x4  = __attribute__((ext_vector_type(4))) float;
typedef unsigned short u16;

__device__ __forceinline__ u16 f2bf(float f) {
  union { float f; unsigned u; } v; v.f = f;
  unsigned r = v.u + 0x7FFFu + ((v.u >> 16) & 1u);   // RNE
  return (u16)(r >> 16);
}
__device__ __forceinline__ float bf2f(u16 h) {
  union { unsigned u; float f; } v; v.u = ((unsigned)h) << 16; return v.f;
}
__device__ __forceinline__ void gload16(const void* gsrc, void* ldst) {
  __builtin_amdgcn_global_load_lds(
      (const __attribute__((address_space(1))) void*)gsrc,
      (__attribute__((address_space(3))) void*)ldst, 16, 0, 0);
}

// ---------------- 64x64 transpose+convert body (vectorized) ----------------
__device__ __forceinline__ void tcvt64_body(const float* __restrict__ src,
                                            u16* __restrict__ dst, int R, int C,
                                            int e, int rb, int cb, char* smem) {
  u16 (*tile)[65] = (u16(*)[65])smem;
  size_t off = (size_t)e * R * C;
  int t = threadIdx.x;
  int r = t >> 4, cq = (t & 15) << 2;
#pragma unroll
  for (int k = 0; k < 4; k++) {
    int rr = r + k * 16;
    float4 v = *(const float4*)(src + off + (size_t)(rb + rr) * C + cb + cq);
    tile[rr][cq] = f2bf(v.x);
    tile[rr][cq + 1] = f2bf(v.y);
    tile[rr][cq + 2] = f2bf(v.z);
    tile[rr][cq + 3] = f2bf(v.w);
  }
  __syncthreads();
  int r4 = (t & 15) << 2, c0 = t >> 4;
#pragma unroll
  for (int j = 0; j < 4; j++) {
    int c = c0 + j * 16;
    ushort4 o;
    o.x = tile[r4][c]; o.y = tile[r4 + 1][c];
    o.z = tile[r4 + 2][c]; o.w = tile[r4 + 3][c];
    *(ushort4*)(dst + off + (size_t)(cb + c) * R + rb + r4) = o;
  }
}

// ---------------- prep: fused gating + W1-tcvt + out-zeroing ----------------
// grid = GBLK + 8192 + 4096. [0,GBLK): gating; [GBLK,GBLK+8192): W1 tcvt;
// rest: zero out[0..8388608) (needed for the atomic combine in gemm2).
__global__ __launch_bounds__(256) void prep(
    const float* __restrict__ X, const float* __restrict__ TP,
    const float* __restrict__ Wg, const float* __restrict__ bg,
    const float* __restrict__ Wt, const float* __restrict__ bgt,
    const float* __restrict__ alphaP,
    const float* __restrict__ W1,
    u16* __restrict__ Xb, u16* __restrict__ W1T, int* meta,
    float* __restrict__ out) {
  __shared__ char smem[41216];
  int bid = blockIdx.x;
  if (bid >= GBLK + 8192) {      // zero out: 4096 blocks x 512 float4
    size_t base = (size_t)(bid - GBLK - 8192) * 2048 + threadIdx.x * 4;
    *(float4*)(out + base) = make_float4(0.f, 0.f, 0.f, 0.f);
    *(float4*)(out + base + 1024) = make_float4(0.f, 0.f, 0.f, 0.f);
    return;
  }
  if (bid >= GBLK) {
    int loc = bid - GBLK;   // W1 [e][1024][4096] -> W1T [e][4096][1024]
    int e = loc >> 10, t10 = loc & 1023;
    tcvt64_body(W1, W1T, D_DIM, F_DIM, e, (t10 & 15) << 6, (t10 >> 4) << 6, smem);
    return;
  }
  // ---- gating (32 tokens/block, no atomics) ----
  float* WgT = (float*)smem;                    // [e][d] 32KB
  float* WtT = (float*)(smem + 32768);          // 8KB
  float* wsP = (float*)(smem + 40960);          // [4][8]
  int*   wsC = (int*)(smem + 41088);            // [4][8]
  int tid = threadIdx.x;
  for (int i = tid; i < E_EXP * D_DIM; i += 256) { int d = i >> 3, e = i & 7; WgT[e * D_DIM + d] = Wg[i]; }
  for (int i = tid; i < E_EXP * DT_DIM; i += 256) { int d = i >> 3, e = i & 7; WtT[e * DT_DIM + d] = Wt[i]; }
  __syncthreads();
  int lane = tid & 63, wid = tid >> 6;
  int tb = bid * 32;
  int b = tb >> 11;  // S=2048
  float alpha = alphaP[0];

  float tac[8] = {};
#pragma unroll
  for (int i = 0; i < 4; i++) {
    int d = lane + i * 64;
    float x = TP[b * DT_DIM + d];
#pragma unroll
    for (int e = 0; e < 8; e++) tac[e] += x * WtT[e * DT_DIM + d];
  }
  for (int off = 32; off > 0; off >>= 1)
#pragma unroll
    for (int e = 0; e < 8; e++) tac[e] += __shfl_xor(tac[e], off);
  float tl[8];
#pragma unroll
  for (int e = 0; e < 8; e++) tl[e] = alpha * (tac[e] + bgt[e]);

  float psum[8] = {};
  int   cnt[8] = {};
  for (int i = 0; i < 8; i++) {
    int t = tb + wid * 8 + i;
    const float* xr = X + (size_t)t * D_DIM;
    float acc[8] = {};
    u16 xb[16];
#pragma unroll 4
    for (int j = 0; j < 16; j++) {
      int d = lane + j * 64;
      float x = xr[d];
      xb[j] = f2bf(x);
#pragma unroll
      for (int e = 0; e < 8; e++) acc[e] += x * WgT[e * D_DIM + d];
    }
#pragma unroll
    for (int j = 0; j < 16; j++) Xb[(size_t)t * D_DIM + lane + j * 64] = xb[j];
    for (int off = 32; off > 0; off >>= 1)
#pragma unroll
      for (int e = 0; e < 8; e++) acc[e] += __shfl_xor(acc[e], off);
    float gl[8];
#pragma unroll
    for (int e = 0; e < 8; e++) gl[e] = (1.f - alpha) * (acc[e] + bg[e]) + tl[e];
    int e1 = 0;
#pragma unroll
    for (int e = 1; e < 8; e++) if (gl[e] > gl[e1]) e1 = e;
    int es = (e1 == 0) ? 1 : 0;
#pragma unroll
    for (int e = 0; e < 8; e++) if (e != e1 && gl[e] > gl[es]) es = e;
    float mx = gl[0];
#pragma unroll
    for (int e = 1; e < 8; e++) mx = fmaxf(mx, gl[e]);
    float pe[8], se = 0.f;
#pragma unroll
    for (int e = 0; e < 8; e++) { pe[e] = __expf(gl[e] - mx); se += pe[e]; }
    float inv = 1.f / se;
    if (lane == 0) {
#pragma unroll
      for (int e = 0; e < 8; e++) psum[e] += pe[e] * inv;
      cnt[e1]++; cnt[es]++;
      float w1 = 1.f / (1.f + __expf(gl[es] - gl[e1]));
      meta[MO_ROUTEE / 4 + 2 * t] = e1;
      meta[MO_ROUTEE / 4 + 2 * t + 1] = es;
      ((float*)meta)[MO_ROUTEW / 4 + 2 * t] = w1;
      ((float*)meta)[MO_ROUTEW / 4 + 2 * t + 1] = 1.f - w1;
    }
  }
  if (lane == 0) {
#pragma unroll
    for (int e = 0; e < 8; e++) { wsP[wid * 8 + e] = psum[e]; wsC[wid * 8 + e] = cnt[e]; }
  }
  __syncthreads();
  if (tid < 8) {
    float p = wsP[tid] + wsP[8 + tid] + wsP[16 + tid] + wsP[24 + tid];
    int   c = wsC[tid] + wsC[8 + tid] + wsC[16 + tid] + wsC[24 + tid];
    ((float*)meta)[MO_PARTP / 4 + bid * 8 + tid] = p;
    meta[MO_PARTC / 4 + bid * 8 + tid] = c;
  }
}

// ---------------- standalone W2 tcvt (small-ws fallback, into WT) ----------
__global__ __launch_bounds__(256) void tcvt2k(const float* __restrict__ W2,
                                              u16* __restrict__ W2T) {
  __shared__ char smem[8448];
  int loc = blockIdx.x;
  int e = loc >> 10, t10 = loc & 1023;
  tcvt64_body(W2, W2T, F_DIM, D_DIM, e, (t10 >> 4) << 6, (t10 & 15) << 6, smem);
}

// ---------------- plan ----------------
__global__ void plan(int* meta, float* out) {
  __shared__ float sp[8];
  __shared__ int   sc[8];
  int tid = threadIdx.x;
  if (blockIdx.x != 0) return;
  if (tid < 8) {
    const float* pp = (const float*)meta + MO_PARTP / 4;
    const int*   pc = meta + MO_PARTC / 4;
    float p = 0.f; int c = 0;
    for (int b = 0; b < GBLK; b++) { p += pp[b * 8 + tid]; c += pc[b * 8 + tid]; }
    sp[tid] = p; sc[tid] = c;
    meta[MO_FILL / 4 + tid] = 0;
  }
  int* ptok = meta + MO_PTOK / 4;
  float* wsl = (float*)meta + MO_WSLOT / 4;
  for (int i = tid; i < 17408; i += 64) { ptok[i] = 0; wsl[i] = 0.f; }
  __syncthreads();
  if (tid == 0) {
    int* pb = meta + MO_PB / 4;
    int* tileE = meta + MO_TILEE / 4;
    int* tileRB = meta + MO_TILERB / 4;
    int base = 0, nt = 0;
    float la = 0.f;
    for (int e = 0; e < 8; e++) {
      int n = sc[e];
      pb[e] = base;
      int ntl = (n + 127) >> 7;
      for (int i = 0; i < ntl; i++) { tileE[nt] = e; tileRB[nt] = base + (i << 7); nt++; }
      base += ntl << 7;
      la += (sp[e] * (1.f / 8192.f)) * ((float)n * (1.f / 8192.f));
    }
    pb[8] = base;
    meta[MO_NT / 4] = nt;
    out[T_TOK * D_DIM] = la;  // l_aux
  }
}

// ---------------- fill slot lists (wave-aggregated atomics) ----------------
__global__ __launch_bounds__(256) void fillk(int* meta) {
  int t = blockIdx.x * 256 + threadIdx.x;
  int lane = threadIdx.x & 63;
  int* pb = meta + MO_PB / 4;
  int* fl = meta + MO_FILL / 4;
  int* ptok = meta + MO_PTOK / 4;
  int* ts = meta + MO_TSLOT / 4;
  float* wsl = (float*)meta + MO_WSLOT / 4;
  unsigned long long lmask = (1ull << lane) - 1;
#pragma unroll
  for (int k = 0; k < 2; k++) {
    int e = meta[MO_ROUTEE / 4 + 2 * t + k];
    int slot = 0;
    for (int ee = 0; ee < 8; ee++) {
      unsigned long long mask = __ballot(e == ee);
      if (e == ee) {
        int low = __ffsll((long long)mask) - 1;
        int pre = __popcll(mask & lmask);
        int base = 0;
        if (lane == low) base = atomicAdd(&fl[ee], __popcll(mask));
        base = __shfl(base, low);
        slot = pb[ee] + base + pre;
      }
    }
    ptok[slot] = t;
    ts[2 * t + k] = slot;
    wsl[slot] = ((const float*)meta)[MO_ROUTEW / 4 + 2 * t + k];
  }
}

// =====================================================================
// GEMM core (r11/r14 local optimum): 128x128 tile, BK=32, 256 thr,
// 4 waves x 64x64, T2 XOR swizzle (0 conflicts). 3-buffer LDS (48KB),
// distance-2 prefetch, counted vmcnt(4), one barrier per step.
// NEW r15: gemm2's epilogue fuses the combine — per-slot weighted f32
// atomicAdd into out (2 addends/element, order-commutative -> replay-
// deterministic; out zeroed each call by prep's extra blocks). Y buffer
// and the combine kernel are gone.
// =====================================================================

#define BUFA(i) ((char*)smem + (i) * 16384)
#define BUFB(i) ((char*)smem + (i) * 16384 + 8192)

// ---------------- GEMM1 (+ co-scheduled W2 tcvt in big-ws mode) ----------
__global__ __launch_bounds__(256) void gemm1(
    const u16* __restrict__ Xb, const u16* __restrict__ W1T,
    const float* __restrict__ b1, u16* __restrict__ H,
    const float* __restrict__ W2, u16* __restrict__ W2T,
    const int* __restrict__ meta) {
  __shared__ char smem[49152];
  if (blockIdx.x >= 4352) {     // W2 [e][4096][1024] -> W2T [e][1024][4096]
    int loc = blockIdx.x - 4352;
    int e = loc >> 10, t10 = loc & 1023;
    tcvt64_body(W2, W2T, F_DIM, D_DIM, e, (t10 >> 4) << 6, (t10 & 15) << 6, smem);
    return;
  }
  int xcd = blockIdx.x & 7, loc = blockIdx.x >> 3;   // 4352 = 8*544
  int bt = loc >> 2;
  int cb = (xcd * 4 + (loc & 3)) * 128;
  int nt = meta[MO_NT / 4];
  if (bt >= nt) return;
  int e = meta[MO_TILEE / 4 + bt];
  int rb = meta[MO_TILERB / 4 + bt];
  const int* ptok = meta + MO_PTOK / 4;

  int tid = threadIdx.x, lane = tid & 63, wid = tid >> 6;
  int wr = wid >> 1, wc = wid & 1;
  int r0 = tid >> 2;
  int c0 = (((tid & 3) ^ ((r0 >> 1) & 3)) << 3);   // swizzled source granule
  int tok0 = ptok[rb + r0];
  int tok1 = ptok[rb + r0 + 64];
  const u16* gA0 = Xb + (size_t)tok0 * D_DIM + c0;
  const u16* gA1 = Xb + (size_t)tok1 * D_DIM + c0;
  const u16* gB0 = W1T + ((size_t)e * F_DIM + cb + r0) * D_DIM + c0;
  const u16* gB1 = gB0 + (size_t)64 * D_DIM;

#define STAGE_G1(buf, k0)                                  \
  {                                                        \
    gload16(gA0 + (k0), BUFA(buf) + wid * 1024);           \
    gload16(gA1 + (k0), BUFA(buf) + 4096 + wid * 1024);    \
    gload16(gB0 + (k0), BUFB(buf) + wid * 1024);           \
    gload16(gB1 + (k0), BUFB(buf) + 4096 + wid * 1024);    \
  }

  f32x4 acc[4][4] = {};
  int kb = (((lane >> 4) ^ (((lane & 15) >> 1) & 3)) << 3);  // swizzled read granule
  int ra = wr * 64 + (lane & 15);
  int rn = wc * 64 + (lane & 15);
  STAGE_G1(0, 0)
  STAGE_G1(1, 32)
  int cur = 0;
  for (int kt = 0; kt < 32; kt++) {
    if (kt + 1 < 32)
      asm volatile("s_waitcnt vmcnt(4) lgkmcnt(0)" ::: "memory");
    else
      asm volatile("s_waitcnt vmcnt(0) lgkmcnt(0)" ::: "memory");
    __builtin_amdgcn_sched_barrier(0);
    __builtin_amdgcn_s_barrier();
    int nxt = cur + 2; if (nxt >= 3) nxt -= 3;
    if (kt + 2 < 32) STAGE_G1(nxt, (kt + 2) * 32)
    const short* pA = (const short*)BUFA(cur);
    const short* pB = (const short*)BUFB(cur);
    bf16x8 af[4], bfr[4];
#pragma unroll
    for (int m = 0; m < 4; m++)
      af[m] = *(const bf16x8*)((const char*)pA + ((ra + m * 16) * 32 + kb) * 2);
#pragma unroll
    for (int n = 0; n < 4; n++)
      bfr[n] = *(const bf16x8*)((const char*)pB + ((rn + n * 16) * 32 + kb) * 2);
    __builtin_amdgcn_s_setprio(1);
#pragma unroll
    for (int m = 0; m < 4; m++)
#pragma unroll
      for (int n = 0; n < 4; n++)
        acc[m][n] = __builtin_amdgcn_mfma_f32_16x16x32_bf16(af[m], bfr[n], acc[m][n], 0, 0, 0);
    __builtin_amdgcn_s_setprio(0);
    cur = cur + 1 == 3 ? 0 : cur + 1;
  }
  int rbase = wr * 64 + ((lane >> 4) << 2);
  int cbase = cb + wc * 64 + (lane & 15);
#pragma unroll
  for (int m = 0; m < 4; m++)
#pragma unroll
    for (int n = 0; n < 4; n++) {
      int f = cbase + n * 16;
      float bias = b1[e * F_DIM + f];
#pragma unroll
      for (int r = 0; r < 4; r++) {
        int p = rb + rbase + m * 16 + r;
        float v = acc[m][n][r] + bias;
        float s = v * (1.0f / (1.0f + __expf(-v)));
        H[(size_t)p * F_DIM + f] = f2bf(s);
      }
    }
}

// ---------------- GEMM2: out[tok] += w * (h @ W2[e] + b2[e]) ----------------
__global__ __launch_bounds__(256) void gemm2(
    const u16* __restrict__ H, const u16* __restrict__ W2T,
    const float* __restrict__ b2, float* __restrict__ out,
    const int* __restrict__ meta) {
  __shared__ char smem[49152];
  int id = blockIdx.x;
  int wg = (id & 7) * 136 + (id >> 3);   // bijective, 1088 = 8*136
  int bt = wg >> 3;
  int cb = (wg & 7) * 128;
  int nt = meta[MO_NT / 4];
  if (bt >= nt) return;
  int e = meta[MO_TILEE / 4 + bt];
  int rb = meta[MO_TILERB / 4 + bt];
  int tid = threadIdx.x, lane = tid & 63, wid = tid >> 6;
  int wr = wid >> 1, wc = wid & 1;
  int r0 = tid >> 2;
  int c0 = (((tid & 3) ^ ((r0 >> 1) & 3)) << 3);   // swizzled source granule
  const u16* gA0 = H + (size_t)(rb + r0) * F_DIM + c0;
  const u16* gA1 = gA0 + (size_t)64 * F_DIM;
  const u16* gB0 = W2T + ((size_t)e * D_DIM + cb + r0) * F_DIM + c0;
  const u16* gB1 = gB0 + (size_t)64 * F_DIM;

#define STAGE_G2(buf, k0)                                  \
  {                                                        \
    gload16(gA0 + (k0), BUFA(buf) + wid * 1024);           \
    gload16(gA1 + (k0), BUFA(buf) + 4096 + wid * 1024);    \
    gload16(gB0 + (k0), BUFB(buf) + wid * 1024);           \
    gload16(gB1 + (k0), BUFB(buf) + 4096 + wid * 1024);    \
  }

  f32x4 acc[4][4] = {};
  int kb = (((lane >> 4) ^ (((lane & 15) >> 1) & 3)) << 3);  // swizzled read granule
  int ra = wr * 64 + (lane & 15);
  int rn = wc * 64 + (lane & 15);
  STAGE_G2(0, 0)
  STAGE_G2(1, 32)
  int cur = 0;
  for (int kt = 0; kt < 128; kt++) {
    if (kt + 1 < 128)
      asm volatile("s_waitcnt vmcnt(4) lgkmcnt(0)" ::: "memory");
    else
      asm volatile("s_waitcnt vmcnt(0) lgkmcnt(0)" ::: "memory");
    __builtin_amdgcn_sched_barrier(0);
    __builtin_amdgcn_s_barrier();
    int nxt = cur + 2; if (nxt >= 3) nxt -= 3;
    if (kt + 2 < 128) STAGE_G2(nxt, (kt + 2) * 32)
    const short* pA = (const short*)BUFA(cur);
    const short* pB = (const short*)BUFB(cur);
    bf16x8 af[4], bfr[4];
#pragma unroll
    for (int m = 0; m < 4; m++)
      af[m] = *(const bf16x8*)((const char*)pA + ((ra + m * 16) * 32 + kb) * 2);
#pragma unroll
    for (int n = 0; n < 4; n++)
      bfr[n] = *(const bf16x8*)((const char*)pB + ((rn + n * 16) * 32 + kb) * 2);
    __builtin_amdgcn_s_setprio(1);
#pragma unroll
    for (int m = 0; m < 4; m++)
#pragma unroll
      for (int n = 0; n < 4; n++)
        acc[m][n] = __builtin_amdgcn_mfma_f32_16x16x32_bf16(af[m], bfr[n], acc[m][n], 0, 0, 0);
    __builtin_amdgcn_s_setprio(0);
    cur = cur + 1 == 3 ? 0 : cur + 1;
  }
  // fused combine: out[tok] += w * (acc + bias), 2 addends per element
  int rbase = wr * 64 + ((lane >> 4) << 2);
  int cbase = cb + wc * 64 + (lane & 15);
  const int* ptok = meta + MO_PTOK / 4;
  const float* wsl = (const float*)meta + MO_WSLOT / 4;
  float bias[4];
#pragma unroll
  for (int n = 0; n < 4; n++) bias[n] = b2[e * D_DIM + cbase + n * 16];
#pragma unroll
  for (int m = 0; m < 4; m++)
#pragma unroll
    for (int r = 0; r < 4; r++) {
      int p = rb + rbase + m * 16 + r;
      int tok = ptok[p];
      float w = wsl[p];
      float* orow = out + (size_t)tok * D_DIM + cbase;
#pragma unroll
      for (int n = 0; n < 4; n++)
        atomicAdd(orow + n * 16, w * (acc[m][n][r] + bias[n]));
    }
}

// ---------------- launch ----------------
extern "C" void kernel_launch(void* const* d_in, const int* in_sizes, int n_in,
                              void* d_out, int out_size, void* d_ws, size_t ws_size,
                              hipStream_t stream) {
  (void)in_sizes; (void)n_in; (void)out_size;
  const float* X    = (const float*)d_in[0];
  const float* TP   = (const float*)d_in[1];
  const float* Wg   = (const float*)d_in[2];
  const float* bg   = (const float*)d_in[3];
  const float* Wt   = (const float*)d_in[4];
  const float* bgt  = (const float*)d_in[5];
  const float* alp  = (const float*)d_in[6];
  const float* W1   = (const float*)d_in[7];
  const float* b1   = (const float*)d_in[8];
  const float* W2   = (const float*)d_in[9];
  const float* b2   = (const float*)d_in[10];
  float* out = (float*)d_out;
  char* ws = (char*)d_ws;
  u16* Xb = (u16*)(ws + A_XB);
  u16* WT = (u16*)(ws + A_WT);
  u16* H  = (u16*)(ws + A_H);
  int* meta = (int*)(ws + A_META);

  int big = ws_size >= W2T_NEED;               // room for separate W2T?
  u16* W2T = big ? (u16*)(ws + A_W2T) : WT;

  prep<<<GBLK + 8192 + 4096, 256, 0, stream>>>(X, TP, Wg, bg, Wt, bgt, alp, W1,
                                               Xb, WT, meta, out);
  plan<<<1, 64, 0, stream>>>(meta, out);
  fillk<<<T_TOK / 256, 256, 0, stream>>>(meta);
  gemm1<<<4352 + (big ? 8192 : 0), 256, 0, stream>>>(Xb, WT, b1, H, W2, W2T, meta);
  if (!big) tcvt2k<<<8192, 256, 0, stream>>>(W2, WT);
  gemm2<<<1088, 256, 0, stream>>>(H, W2T, b2, out, meta);
}

// Round 16
// 532.859 us; speedup vs baseline: 1.0705x; 1.0705x over previous
//
#include <hip/hip_runtime.h>

// ---------------- problem constants ----------------
#define T_TOK 8192      // B*S tokens
#define D_DIM 1024
#define F_DIM 4096
#define E_EXP 8
#define DT_DIM 256
#define GBLK 256        // gating blocks (32 tokens each)

// ---------------- workspace layout (bytes) ----------------
#define A_XB   0u                    // bf16 X   [8192][1024]   16,777,216
#define A_WT   16777216u             // bf16 W1T (and W2T in small-ws mode)
#define A_H    83886080u             // bf16 h   [17408][4096] 142,606,336
#define A_Y    226492416u            // bf16 Y   [17408][1024]  35,651,584
#define A_META 262144000u
#define A_W2T  262428928u            // optional separate W2T (needs ws >= ~330MB)
#define W2T_NEED (262428928ull + 67108864ull)
// meta byte offsets
#define MO_FILL   0        // 8 ints (atomic fill cursors)
#define MO_PB     64       // 9 ints (expert segment bases)
#define MO_NT     128      // 1 int
#define MO_PARTP  256      // f32[256][8] per-block prob partials (8KB)
#define MO_PARTC  8448     // int[256][8] per-block count partials (8KB)
#define MO_TILEE  16640    // int[160]
#define MO_TILERB 17664    // int[160]
#define MO_ROUTEE 18688    // int[16384]
#define MO_ROUTEW 84224    // f32[16384]
#define MO_TSLOT  149760   // int[16384]
#define MO_PTOK   215296   // int[17408]
#define META_BYTES 284928

using bf16x8 = __attribute__((ext_vector_type(8))) short;
using f32x4  = __attribute__((ext_vector_type(4))) float;
typedef unsigned short u16;

__device__ __forceinline__ u16 f2bf(float f) {
  union { float f; unsigned u; } v; v.f = f;
  unsigned r = v.u + 0x7FFFu + ((v.u >> 16) & 1u);   // RNE
  return (u16)(r >> 16);
}
__device__ __forceinline__ float bf2f(u16 h) {
  union { unsigned u; float f; } v; v.u = ((unsigned)h) << 16; return v.f;
}
__device__ __forceinline__ void gload16(const void* gsrc, void* ldst) {
  __builtin_amdgcn_global_load_lds(
      (const __attribute__((address_space(1))) void*)gsrc,
      (__attribute__((address_space(3))) void*)ldst, 16, 0, 0);
}

// ---------------- 64x64 transpose+convert body (vectorized) ----------------
__device__ __forceinline__ void tcvt64_body(const float* __restrict__ src,
                                            u16* __restrict__ dst, int R, int C,
                                            int e, int rb, int cb, char* smem) {
  u16 (*tile)[65] = (u16(*)[65])smem;
  size_t off = (size_t)e * R * C;
  int t = threadIdx.x;
  int r = t >> 4, cq = (t & 15) << 2;
#pragma unroll
  for (int k = 0; k < 4; k++) {
    int rr = r + k * 16;
    float4 v = *(const float4*)(src + off + (size_t)(rb + rr) * C + cb + cq);
    tile[rr][cq] = f2bf(v.x);
    tile[rr][cq + 1] = f2bf(v.y);
    tile[rr][cq + 2] = f2bf(v.z);
    tile[rr][cq + 3] = f2bf(v.w);
  }
  __syncthreads();
  int r4 = (t & 15) << 2, c0 = t >> 4;
#pragma unroll
  for (int j = 0; j < 4; j++) {
    int c = c0 + j * 16;
    ushort4 o;
    o.x = tile[r4][c]; o.y = tile[r4 + 1][c];
    o.z = tile[r4 + 2][c]; o.w = tile[r4 + 3][c];
    *(ushort4*)(dst + off + (size_t)(cb + c) * R + rb + r4) = o;
  }
}

// ---------------- prep: fused gating + W1-tcvt ----------------
// grid = GBLK + 8192. blocks [0,GBLK): gating; next 8192: W1 tcvt.
__global__ __launch_bounds__(256) void prep(
    const float* __restrict__ X, const float* __restrict__ TP,
    const float* __restrict__ Wg, const float* __restrict__ bg,
    const float* __restrict__ Wt, const float* __restrict__ bgt,
    const float* __restrict__ alphaP,
    const float* __restrict__ W1,
    u16* __restrict__ Xb, u16* __restrict__ W1T, int* meta) {
  __shared__ char smem[41216];
  int bid = blockIdx.x;
  if (bid >= GBLK) {
    int loc = bid - GBLK;   // W1 [e][1024][4096] -> W1T [e][4096][1024]
    int e = loc >> 10, t10 = loc & 1023;
    tcvt64_body(W1, W1T, D_DIM, F_DIM, e, (t10 & 15) << 6, (t10 >> 4) << 6, smem);
    return;
  }
  // ---- gating (32 tokens/block, no atomics) ----
  float* WgT = (float*)smem;                    // [e][d] 32KB
  float* WtT = (float*)(smem + 32768);          // 8KB
  float* wsP = (float*)(smem + 40960);          // [4][8]
  int*   wsC = (int*)(smem + 41088);            // [4][8]
  int tid = threadIdx.x;
  for (int i = tid; i < E_EXP * D_DIM; i += 256) { int d = i >> 3, e = i & 7; WgT[e * D_DIM + d] = Wg[i]; }
  for (int i = tid; i < E_EXP * DT_DIM; i += 256) { int d = i >> 3, e = i & 7; WtT[e * DT_DIM + d] = Wt[i]; }
  __syncthreads();
  int lane = tid & 63, wid = tid >> 6;
  int tb = bid * 32;
  int b = tb >> 11;  // S=2048
  float alpha = alphaP[0];

  float tac[8] = {};
#pragma unroll
  for (int i = 0; i < 4; i++) {
    int d = lane + i * 64;
    float x = TP[b * DT_DIM + d];
#pragma unroll
    for (int e = 0; e < 8; e++) tac[e] += x * WtT[e * DT_DIM + d];
  }
  for (int off = 32; off > 0; off >>= 1)
#pragma unroll
    for (int e = 0; e < 8; e++) tac[e] += __shfl_xor(tac[e], off);
  float tl[8];
#pragma unroll
  for (int e = 0; e < 8; e++) tl[e] = alpha * (tac[e] + bgt[e]);

  float psum[8] = {};
  int   cnt[8] = {};
  for (int i = 0; i < 8; i++) {
    int t = tb + wid * 8 + i;
    const float* xr = X + (size_t)t * D_DIM;
    float acc[8] = {};
    u16 xb[16];
#pragma unroll 4
    for (int j = 0; j < 16; j++) {
      int d = lane + j * 64;
      float x = xr[d];
      xb[j] = f2bf(x);
#pragma unroll
      for (int e = 0; e < 8; e++) acc[e] += x * WgT[e * D_DIM + d];
    }
#pragma unroll
    for (int j = 0; j < 16; j++) Xb[(size_t)t * D_DIM + lane + j * 64] = xb[j];
    for (int off = 32; off > 0; off >>= 1)
#pragma unroll
      for (int e = 0; e < 8; e++) acc[e] += __shfl_xor(acc[e], off);
    float gl[8];
#pragma unroll
    for (int e = 0; e < 8; e++) gl[e] = (1.f - alpha) * (acc[e] + bg[e]) + tl[e];
    int e1 = 0;
#pragma unroll
    for (int e = 1; e < 8; e++) if (gl[e] > gl[e1]) e1 = e;
    int es = (e1 == 0) ? 1 : 0;
#pragma unroll
    for (int e = 0; e < 8; e++) if (e != e1 && gl[e] > gl[es]) es = e;
    float mx = gl[0];
#pragma unroll
    for (int e = 1; e < 8; e++) mx = fmaxf(mx, gl[e]);
    float pe[8], se = 0.f;
#pragma unroll
    for (int e = 0; e < 8; e++) { pe[e] = __expf(gl[e] - mx); se += pe[e]; }
    float inv = 1.f / se;
    if (lane == 0) {
#pragma unroll
      for (int e = 0; e < 8; e++) psum[e] += pe[e] * inv;
      cnt[e1]++; cnt[es]++;
      float w1 = 1.f / (1.f + __expf(gl[es] - gl[e1]));
      meta[MO_ROUTEE / 4 + 2 * t] = e1;
      meta[MO_ROUTEE / 4 + 2 * t + 1] = es;
      ((float*)meta)[MO_ROUTEW / 4 + 2 * t] = w1;
      ((float*)meta)[MO_ROUTEW / 4 + 2 * t + 1] = 1.f - w1;
    }
  }
  if (lane == 0) {
#pragma unroll
    for (int e = 0; e < 8; e++) { wsP[wid * 8 + e] = psum[e]; wsC[wid * 8 + e] = cnt[e]; }
  }
  __syncthreads();
  if (tid < 8) {
    float p = wsP[tid] + wsP[8 + tid] + wsP[16 + tid] + wsP[24 + tid];
    int   c = wsC[tid] + wsC[8 + tid] + wsC[16 + tid] + wsC[24 + tid];
    ((float*)meta)[MO_PARTP / 4 + bid * 8 + tid] = p;
    meta[MO_PARTC / 4 + bid * 8 + tid] = c;
  }
}

// ---------------- standalone W2 tcvt (small-ws fallback, into WT) ----------
__global__ __launch_bounds__(256) void tcvt2k(const float* __restrict__ W2,
                                              u16* __restrict__ W2T) {
  __shared__ char smem[8448];
  int loc = blockIdx.x;
  int e = loc >> 10, t10 = loc & 1023;
  tcvt64_body(W2, W2T, F_DIM, D_DIM, e, (t10 >> 4) << 6, (t10 & 15) << 6, smem);
}

// ---------------- plan ----------------
__global__ void plan(int* meta, float* out) {
  __shared__ float sp[8];
  __shared__ int   sc[8];
  int tid = threadIdx.x;
  if (blockIdx.x != 0) return;
  if (tid < 8) {
    const float* pp = (const float*)meta + MO_PARTP / 4;
    const int*   pc = meta + MO_PARTC / 4;
    float p = 0.f; int c = 0;
    for (int b = 0; b < GBLK; b++) { p += pp[b * 8 + tid]; c += pc[b * 8 + tid]; }
    sp[tid] = p; sc[tid] = c;
    meta[MO_FILL / 4 + tid] = 0;
  }
  int* ptok = meta + MO_PTOK / 4;
  for (int i = tid; i < 17408; i += 64) ptok[i] = 0;
  __syncthreads();
  if (tid == 0) {
    int* pb = meta + MO_PB / 4;
    int* tileE = meta + MO_TILEE / 4;
    int* tileRB = meta + MO_TILERB / 4;
    int base = 0, nt = 0;
    float la = 0.f;
    for (int e = 0; e < 8; e++) {
      int n = sc[e];
      pb[e] = base;
      int ntl = (n + 127) >> 7;
      for (int i = 0; i < ntl; i++) { tileE[nt] = e; tileRB[nt] = base + (i << 7); nt++; }
      base += ntl << 7;
      la += (sp[e] * (1.f / 8192.f)) * ((float)n * (1.f / 8192.f));
    }
    pb[8] = base;
    meta[MO_NT / 4] = nt;
    out[T_TOK * D_DIM] = la;  // l_aux
  }
}

// ---------------- fill slot lists (wave-aggregated atomics) ----------------
__global__ __launch_bounds__(256) void fillk(int* meta) {
  int t = blockIdx.x * 256 + threadIdx.x;
  int lane = threadIdx.x & 63;
  int* pb = meta + MO_PB / 4;
  int* fl = meta + MO_FILL / 4;
  int* ptok = meta + MO_PTOK / 4;
  int* ts = meta + MO_TSLOT / 4;
  unsigned long long lmask = (1ull << lane) - 1;
#pragma unroll
  for (int k = 0; k < 2; k++) {
    int e = meta[MO_ROUTEE / 4 + 2 * t + k];
    int slot = 0;
    for (int ee = 0; ee < 8; ee++) {
      unsigned long long mask = __ballot(e == ee);
      if (e == ee) {
        int low = __ffsll((long long)mask) - 1;
        int pre = __popcll(mask & lmask);
        int base = 0;
        if (lane == low) base = atomicAdd(&fl[ee], __popcll(mask));
        base = __shfl(base, low);
        slot = pb[ee] + base + pre;
      }
    }
    ptok[slot] = t;
    ts[2 * t + k] = slot;
  }
}

// =====================================================================
// GEMM core (r11/r14 local optimum): 128x128 tile, BK=32, 256 thr,
// 4 waves x 64x64, T2 XOR swizzle (0 conflicts). 3-buffer LDS (48KB),
// distance-2 prefetch, counted vmcnt(4), one barrier per step.
// r15's atomic-combine fusion REGRESSED (+37us in gemm2: RMW write
// doubling + occupancy drop) — reverted to separate combine kernel.
// =====================================================================

#define BUFA(i) ((char*)smem + (i) * 16384)
#define BUFB(i) ((char*)smem + (i) * 16384 + 8192)

// ---------------- GEMM1 (+ co-scheduled W2 tcvt in big-ws mode) ----------
__global__ __launch_bounds__(256) void gemm1(
    const u16* __restrict__ Xb, const u16* __restrict__ W1T,
    const float* __restrict__ b1, u16* __restrict__ H,
    const float* __restrict__ W2, u16* __restrict__ W2T,
    const int* __restrict__ meta) {
  __shared__ char smem[49152];
  if (blockIdx.x >= 4352) {     // W2 [e][4096][1024] -> W2T [e][1024][4096]
    int loc = blockIdx.x - 4352;
    int e = loc >> 10, t10 = loc & 1023;
    tcvt64_body(W2, W2T, F_DIM, D_DIM, e, (t10 >> 4) << 6, (t10 & 15) << 6, smem);
    return;
  }
  int xcd = blockIdx.x & 7, loc = blockIdx.x >> 3;   // 4352 = 8*544
  int bt = loc >> 2;
  int cb = (xcd * 4 + (loc & 3)) * 128;
  int nt = meta[MO_NT / 4];
  if (bt >= nt) return;
  int e = meta[MO_TILEE / 4 + bt];
  int rb = meta[MO_TILERB / 4 + bt];
  const int* ptok = meta + MO_PTOK / 4;

  int tid = threadIdx.x, lane = tid & 63, wid = tid >> 6;
  int wr = wid >> 1, wc = wid & 1;
  int r0 = tid >> 2;
  int c0 = (((tid & 3) ^ ((r0 >> 1) & 3)) << 3);   // swizzled source granule
  int tok0 = ptok[rb + r0];
  int tok1 = ptok[rb + r0 + 64];
  const u16* gA0 = Xb + (size_t)tok0 * D_DIM + c0;
  const u16* gA1 = Xb + (size_t)tok1 * D_DIM + c0;
  const u16* gB0 = W1T + ((size_t)e * F_DIM + cb + r0) * D_DIM + c0;
  const u16* gB1 = gB0 + (size_t)64 * D_DIM;

#define STAGE_G1(buf, k0)                                  \
  {                                                        \
    gload16(gA0 + (k0), BUFA(buf) + wid * 1024);           \
    gload16(gA1 + (k0), BUFA(buf) + 4096 + wid * 1024);    \
    gload16(gB0 + (k0), BUFB(buf) + wid * 1024);           \
    gload16(gB1 + (k0), BUFB(buf) + 4096 + wid * 1024);    \
  }

  f32x4 acc[4][4] = {};
  int kb = (((lane >> 4) ^ (((lane & 15) >> 1) & 3)) << 3);  // swizzled read granule
  int ra = wr * 64 + (lane & 15);
  int rn = wc * 64 + (lane & 15);
  STAGE_G1(0, 0)
  STAGE_G1(1, 32)
  int cur = 0;
  for (int kt = 0; kt < 32; kt++) {
    if (kt + 1 < 32)
      asm volatile("s_waitcnt vmcnt(4) lgkmcnt(0)" ::: "memory");
    else
      asm volatile("s_waitcnt vmcnt(0) lgkmcnt(0)" ::: "memory");
    __builtin_amdgcn_sched_barrier(0);
    __builtin_amdgcn_s_barrier();
    int nxt = cur + 2; if (nxt >= 3) nxt -= 3;
    if (kt + 2 < 32) STAGE_G1(nxt, (kt + 2) * 32)
    const short* pA = (const short*)BUFA(cur);
    const short* pB = (const short*)BUFB(cur);
    bf16x8 af[4], bfr[4];
#pragma unroll
    for (int m = 0; m < 4; m++)
      af[m] = *(const bf16x8*)((const char*)pA + ((ra + m * 16) * 32 + kb) * 2);
#pragma unroll
    for (int n = 0; n < 4; n++)
      bfr[n] = *(const bf16x8*)((const char*)pB + ((rn + n * 16) * 32 + kb) * 2);
    __builtin_amdgcn_s_setprio(1);
#pragma unroll
    for (int m = 0; m < 4; m++)
#pragma unroll
      for (int n = 0; n < 4; n++)
        acc[m][n] = __builtin_amdgcn_mfma_f32_16x16x32_bf16(af[m], bfr[n], acc[m][n], 0, 0, 0);
    __builtin_amdgcn_s_setprio(0);
    cur = cur + 1 == 3 ? 0 : cur + 1;
  }
  int rbase = wr * 64 + ((lane >> 4) << 2);
  int cbase = cb + wc * 64 + (lane & 15);
#pragma unroll
  for (int m = 0; m < 4; m++)
#pragma unroll
    for (int n = 0; n < 4; n++) {
      int f = cbase + n * 16;
      float bias = b1[e * F_DIM + f];
#pragma unroll
      for (int r = 0; r < 4; r++) {
        int p = rb + rbase + m * 16 + r;
        float v = acc[m][n][r] + bias;
        float s = v * (1.0f / (1.0f + __expf(-v)));
        H[(size_t)p * F_DIM + f] = f2bf(s);
      }
    }
}

// ---------------- GEMM2: Y = h @ W2[e] + b2[e] ----------------
__global__ __launch_bounds__(256) void gemm2(
    const u16* __restrict__ H, const u16* __restrict__ W2T,
    const float* __restrict__ b2, u16* __restrict__ Y, const int* __restrict__ meta) {
  __shared__ char smem[49152];
  int id = blockIdx.x;
  int wg = (id & 7) * 136 + (id >> 3);   // bijective, 1088 = 8*136
  int bt = wg >> 3;
  int cb = (wg & 7) * 128;
  int nt = meta[MO_NT / 4];
  if (bt >= nt) return;
  int e = meta[MO_TILEE / 4 + bt];
  int rb = meta[MO_TILERB / 4 + bt];
  int tid = threadIdx.x, lane = tid & 63, wid = tid >> 6;
  int wr = wid >> 1, wc = wid & 1;
  int r0 = tid >> 2;
  int c0 = (((tid & 3) ^ ((r0 >> 1) & 3)) << 3);   // swizzled source granule
  const u16* gA0 = H + (size_t)(rb + r0) * F_DIM + c0;
  const u16* gA1 = gA0 + (size_t)64 * F_DIM;
  const u16* gB0 = W2T + ((size_t)e * D_DIM + cb + r0) * F_DIM + c0;
  const u16* gB1 = gB0 + (size_t)64 * F_DIM;

#define STAGE_G2(buf, k0)                                  \
  {                                                        \
    gload16(gA0 + (k0), BUFA(buf) + wid * 1024);           \
    gload16(gA1 + (k0), BUFA(buf) + 4096 + wid * 1024);    \
    gload16(gB0 + (k0), BUFB(buf) + wid * 1024);           \
    gload16(gB1 + (k0), BUFB(buf) + 4096 + wid * 1024);    \
  }

  f32x4 acc[4][4] = {};
  int kb = (((lane >> 4) ^ (((lane & 15) >> 1) & 3)) << 3);  // swizzled read granule
  int ra = wr * 64 + (lane & 15);
  int rn = wc * 64 + (lane & 15);
  STAGE_G2(0, 0)
  STAGE_G2(1, 32)
  int cur = 0;
  for (int kt = 0; kt < 128; kt++) {
    if (kt + 1 < 128)
      asm volatile("s_waitcnt vmcnt(4) lgkmcnt(0)" ::: "memory");
    else
      asm volatile("s_waitcnt vmcnt(0) lgkmcnt(0)" ::: "memory");
    __builtin_amdgcn_sched_barrier(0);
    __builtin_amdgcn_s_barrier();
    int nxt = cur + 2; if (nxt >= 3) nxt -= 3;
    if (kt + 2 < 128) STAGE_G2(nxt, (kt + 2) * 32)
    const short* pA = (const short*)BUFA(cur);
    const short* pB = (const short*)BUFB(cur);
    bf16x8 af[4], bfr[4];
#pragma unroll
    for (int m = 0; m < 4; m++)
      af[m] = *(const bf16x8*)((const char*)pA + ((ra + m * 16) * 32 + kb) * 2);
#pragma unroll
    for (int n = 0; n < 4; n++)
      bfr[n] = *(const bf16x8*)((const char*)pB + ((rn + n * 16) * 32 + kb) * 2);
    __builtin_amdgcn_s_setprio(1);
#pragma unroll
    for (int m = 0; m < 4; m++)
#pragma unroll
      for (int n = 0; n < 4; n++)
        acc[m][n] = __builtin_amdgcn_mfma_f32_16x16x32_bf16(af[m], bfr[n], acc[m][n], 0, 0, 0);
    __builtin_amdgcn_s_setprio(0);
    cur = cur + 1 == 3 ? 0 : cur + 1;
  }
  int rbase = wr * 64 + ((lane >> 4) << 2);
  int cbase = cb + wc * 64 + (lane & 15);
#pragma unroll
  for (int m = 0; m < 4; m++)
#pragma unroll
    for (int n = 0; n < 4; n++) {
      int d = cbase + n * 16;
      float bias = b2[e * D_DIM + d];
#pragma unroll
      for (int r = 0; r < 4; r++) {
        int p = rb + rbase + m * 16 + r;
        Y[(size_t)p * D_DIM + d] = f2bf(acc[m][n][r] + bias);
      }
    }
}

// ---------------- combine: out[t] = w1*Y[s1] + w2*Y[s2] ----------------
__global__ __launch_bounds__(256) void combine(const u16* __restrict__ Y,
                                               const int* __restrict__ meta,
                                               float* __restrict__ out) {
  int t = blockIdx.x;
  const int* ts = meta + MO_TSLOT / 4;
  const float* rw = (const float*)meta + MO_ROUTEW / 4;
  int s1 = ts[2 * t], s2 = ts[2 * t + 1];
  float w1 = rw[2 * t], w2 = rw[2 * t + 1];
  int d0 = threadIdx.x * 4;
  ushort4 a = *(const ushort4*)(Y + (size_t)s1 * D_DIM + d0);
  ushort4 b = *(const ushort4*)(Y + (size_t)s2 * D_DIM + d0);
  float4 v;
  v.x = w1 * bf2f(a.x) + w2 * bf2f(b.x);
  v.y = w1 * bf2f(a.y) + w2 * bf2f(b.y);
  v.z = w1 * bf2f(a.z) + w2 * bf2f(b.z);
  v.w = w1 * bf2f(a.w) + w2 * bf2f(b.w);
  *(float4*)(out + (size_t)t * D_DIM + d0) = v;
}

// ---------------- launch ----------------
extern "C" void kernel_launch(void* const* d_in, const int* in_sizes, int n_in,
                              void* d_out, int out_size, void* d_ws, size_t ws_size,
                              hipStream_t stream) {
  (void)in_sizes; (void)n_in; (void)out_size;
  const float* X    = (const float*)d_in[0];
  const float* TP   = (const float*)d_in[1];
  const float* Wg   = (const float*)d_in[2];
  const float* bg   = (const float*)d_in[3];
  const float* Wt   = (const float*)d_in[4];
  const float* bgt  = (const float*)d_in[5];
  const float* alp  = (const float*)d_in[6];
  const float* W1   = (const float*)d_in[7];
  const float* b1   = (const float*)d_in[8];
  const float* W2   = (const float*)d_in[9];
  const float* b2   = (const float*)d_in[10];
  float* out = (float*)d_out;
  char* ws = (char*)d_ws;
  u16* Xb = (u16*)(ws + A_XB);
  u16* WT = (u16*)(ws + A_WT);
  u16* H  = (u16*)(ws + A_H);
  u16* Y  = (u16*)(ws + A_Y);
  int* meta = (int*)(ws + A_META);

  int big = ws_size >= W2T_NEED;               // room for separate W2T?
  u16* W2T = big ? (u16*)(ws + A_W2T) : WT;

  prep<<<GBLK + 8192, 256, 0, stream>>>(X, TP, Wg, bg, Wt, bgt, alp, W1,
                                        Xb, WT, meta);
  plan<<<1, 64, 0, stream>>>(meta, out);
  fillk<<<T_TOK / 256, 256, 0, stream>>>(meta);
  gemm1<<<4352 + (big ? 8192 : 0), 256, 0, stream>>>(Xb, WT, b1, H, W2, W2T, meta);
  if (!big) tcvt2k<<<8192, 256, 0, stream>>>(W2, WT);
  gemm2<<<1088, 256, 0, stream>>>(H, W2T, b2, Y, meta);
  combine<<<T_TOK, 256, 0, stream>>>(Y, meta, out);
}